// Round 11
// baseline (99.109 us; speedup 1.0000x reference)
//
#include <hip/hip_runtime.h>

#define HW   16384
#define CH   256
#define WD   128
#define NPTS 4

typedef _Float16 half8 __attribute__((ext_vector_type(8)));
typedef _Float16 half4 __attribute__((ext_vector_type(4)));
typedef float    f32x4 __attribute__((ext_vector_type(4)));

// ---- workspace layout (bytes) ----
#define WS_XT    0ull            // _Float16 [65536][256]  32 MB  (x transposed, per-pixel)
#define WS_WQK   33554432ull     // _Float16 [256][256]    128 KB (A = Wk^T Wq)
#define WS_WV    33685504ull     // _Float16 [256][256]    128 KB
#define WS_WOQ   33816576ull     // float    [256][8]      8 KB
#define WS_BOF   33824768ull     // float    [8] (64 B pad)
#define WS_CVEC  33824832ull     // float    [256]
#define WS_DVEC  33825856ull     // float    [256]
#define WS_SC    33826880ull     // float    [1] (64 B pad)
#define WS_SVEC  33826944ull     // float    [65536]  256 KB
#define WS_IDX   34089088ull     // int      [4][4][16384]  1 MB

// ---------- weight prep: A=Wk^T Wq fp16, cvec, Wv fp16, woq/bof, dvec, sconst ----------
__global__ void k_wprep(const float* __restrict__ Wq, const float* __restrict__ bq,
                        const float* __restrict__ Wk, const float* __restrict__ bk,
                        const float* __restrict__ Wv, const float* __restrict__ bv,
                        const float* __restrict__ Wo, const float* __restrict__ bo,
                        _Float16* __restrict__ wqk16, float* __restrict__ cvec,
                        _Float16* __restrict__ wv16, float* __restrict__ woq,
                        float* __restrict__ bof, float* __restrict__ dvec,
                        float* __restrict__ scst) {
    int bid = blockIdx.x, t = threadIdx.x;
    if (bid < 256) {                 // A[i][t] = sum_o Wk[o][i]*Wq[o][t]
        int i = bid;
        float s = 0.f;
        for (int o = 0; o < 256; o++) s += Wk[o * 256 + i] * Wq[o * 256 + t];
        wqk16[i * 256 + t] = (_Float16)s;
        if (t == 0) {
            float cs = 0.f;
            for (int o = 0; o < 256; o++) cs += Wk[o * 256 + i] * bq[o];
            cvec[i] = cs;
        }
    } else if (bid < 512) {          // Wv -> fp16
        int r = bid - 256;
        wv16[r * 256 + t] = (_Float16)Wv[r * 256 + t];
    } else if (bid < 520) {          // fused offset weights (fp32, discontinuous path)
        int j = bid - 512;
        float s = 0.f;
        for (int o = 0; o < 256; o++) s += Wo[j * 256 + o] * Wq[o * 256 + t];
        woq[t * 8 + j] = s;
        if (t == 0) {
            float tt = bo[j];
            for (int o = 0; o < 256; o++) tt += Wo[j * 256 + o] * bq[o];
            bof[j] = tt;
        }
    } else {                         // dvec[t] = sum_o bk[o]*Wq[o][t]; sconst = bq.bk
        float s = 0.f;
        for (int o = 0; o < 256; o++) s += bk[o] * Wq[o * 256 + t];
        dvec[t] = s;
        if (t == 0) {
            float sc = 0.f;
            for (int o = 0; o < 256; o++) sc += bq[o] * bk[o];
            scst[0] = sc;
        }
    }
}

// ---------- fused: x -> xt fp16, offsets -> idx (pure f32), s_p ----------
__launch_bounds__(256)
__global__ void k_prep(const float* __restrict__ x, const float* __restrict__ woq,
                       const float* __restrict__ bof, const float* __restrict__ dvec,
                       const float* __restrict__ scst,
                       _Float16* __restrict__ xt, int* __restrict__ idxb,
                       float* __restrict__ svec) {
    __shared__ float    wl[256 * 8];
    __shared__ float    dl[256];
    __shared__ float    bl8[8];
    __shared__ _Float16 tile[64][280];      // pitch 560B: b128 writes spread over all 8 slots
    __shared__ float    red[4][64][8];
    __shared__ float    reds[4][64];

    int t = threadIdx.x;
    for (int i = t; i < 256 * 8; i += 256) wl[i] = woq[i];
    dl[t] = dvec[t];
    if (t < 8) bl8[t] = bof[t];
    __syncthreads();

    int b = blockIdx.y;
    int p0 = blockIdx.x * 64;
    int pl = t & 63, cg = t >> 6;
    const float* xb = x + (size_t)b * CH * HW + p0 + pl;

    float acc[8];
    #pragma unroll
    for (int j = 0; j < 8; j++) acc[j] = 0.f;
    float accs = 0.f;

    for (int i0 = 0; i0 < 64; i0 += 8) {
        half8 hv;
        #pragma unroll
        for (int i = 0; i < 8; i++) {
            int c = cg * 64 + i0 + i;
            float xv = xb[(size_t)c * HW];
            hv[i] = (_Float16)xv;
            accs += dl[c] * xv;
            #pragma unroll
            for (int j = 0; j < 8; j++) acc[j] += wl[c * 8 + j] * xv;
        }
        *(half8*)(&tile[pl][cg * 64 + i0]) = hv;
    }
    #pragma unroll
    for (int j = 0; j < 8; j++) red[cg][pl][j] = acc[j];
    reds[cg][pl] = accs;
    __syncthreads();

    {
        int n = cg, p = p0 + pl;
        float sw_ = bl8[2 * n]     + red[0][pl][2 * n]     + red[1][pl][2 * n]
                                   + red[2][pl][2 * n]     + red[3][pl][2 * n];
        float sh_ = bl8[2 * n + 1] + red[0][pl][2 * n + 1] + red[1][pl][2 * n + 1]
                                   + red[2][pl][2 * n + 1] + red[3][pl][2 * n + 1];
        int h = p >> 7, w = p & 127;
        float rw = fminf(fmaxf((float)w + sw_, 0.f), 127.f);
        float rh = fminf(fmaxf((float)h + sh_, 0.f), 127.f);
        idxb[(b * NPTS + n) * HW + p] = ((int)rh) * WD + (int)rw;
        if (cg == 0)
            svec[b * HW + p] = reds[0][pl] + reds[1][pl] + reds[2][pl] + reds[3][pl] + scst[0];
    }

    {
        int row = t >> 2;
        size_t gbase = ((size_t)(b * HW + p0 + row)) * 256;
        #pragma unroll
        for (int s = 0; s < 8; s++) {
            int seg = (t & 3) + s * 4;
            *(uint4*)(xt + gbase + seg * 8) = *(const uint4*)(&tile[row][seg * 8]);
        }
    }
}

// ---------- fused GEMM1 + gather-attn + GEMM2, v6 = r8 + spill-safe T14 ----------
// 512 thr (8 waves), 64 px/block. AQW (32KB): A -> qh -> w in place.
// Bs dbuf (2x16KB). 64.25KB LDS -> 2 blocks/CU.
// Only jj/sv prefetched across phase 1 (10 VGPR). All 16 gather loads issued
// back-to-back at phase-2 top (no value live across a k-loop -> no spill).
__launch_bounds__(512, 4)
__global__ void k_fused(const _Float16* __restrict__ xt, const _Float16* __restrict__ wqk16,
                        const _Float16* __restrict__ wv16, const float* __restrict__ cvec,
                        const float* __restrict__ bv, const int* __restrict__ idxb,
                        const float* __restrict__ svec, float* __restrict__ out) {
    __shared__ _Float16 AQW[64 * 256];      // 32 KB
    __shared__ _Float16 Bs[2][256 * 32];    // 32 KB
    __shared__ float    asf[64];

    int tid = threadIdx.x;
    int b = blockIdx.y;
    int bx = blockIdx.x;
    int logical = (bx & 7) * 32 + (bx >> 3);    // 256 = 8 XCD * 32, bijective
    int p0 = logical * 64;
    size_t mrow0 = (size_t)b * HW + p0;

    int lane = tid & 63, wid = tid >> 6;
    int wr = wid >> 2, wc = wid & 3;
    int g = lane >> 4, r = lane & 15;

    // ---- stage A (64 px x 256 k) into AQW, swizzled ----
    {
        int row = tid >> 3;
        int c0 = tid & 7;
        const uint4* src = (const uint4*)(xt + (mrow0 + row) * 256);
        #pragma unroll
        for (int s = 0; s < 4; s++) {
            int c8 = c0 + s * 8;
            uint4 v = src[c8];
            *(uint4*)(&AQW[(row << 8) + 8 * (c8 ^ (row & 7))]) = v;
        }
    }

    int brow = tid >> 1, bseg = tid & 1;
    int bslot0 = (bseg * 2)     ^ ((brow >> 1) & 3);
    int bslot1 = (bseg * 2 + 1) ^ ((brow >> 1) & 3);
    uint4 br0, br1;

    // prologue: B(0) -> Bs[0]; B(1) -> regs
    {
        const _Float16* p = wqk16 + (size_t)brow * 256 + bseg * 16;
        br0 = *(const uint4*)(p);
        br1 = *(const uint4*)(p + 8);
        *(uint4*)(&Bs[0][brow * 32 + bslot0 * 8]) = br0;
        *(uint4*)(&Bs[0][brow * 32 + bslot1 * 8]) = br1;
        p += 32;
        br0 = *(const uint4*)(p);
        br1 = *(const uint4*)(p + 8);
    }

    // ---- light prefetch across phase 1 (10 VGPR only: indices + svec) ----
    int seg = tid & 15, pslot = tid >> 4;       // 16 consecutive lanes = one pixel
    int jj0[NPTS], jj1[NPTS];
    #pragma unroll
    for (int n = 0; n < NPTS; n++) {
        jj0[n] = idxb[(b * NPTS + n) * HW + p0 + pslot];
        jj1[n] = idxb[(b * NPTS + n) * HW + p0 + 32 + pslot];
    }
    float sv0 = svec[mrow0 + pslot];
    float sv1 = svec[mrow0 + 32 + pslot];
    __syncthreads();

    // ================= phase 1 k-loop: qh = A.x =================
    f32x4 acc[2][4] = {};
    #pragma unroll
    for (int kt = 0; kt < 8; kt++) {
        if (kt < 7) {
            _Float16* B = &Bs[(kt + 1) & 1][0];
            *(uint4*)(&B[brow * 32 + bslot0 * 8]) = br0;
            *(uint4*)(&B[brow * 32 + bslot1 * 8]) = br1;
        }
        if (kt < 6) {
            const _Float16* p = wqk16 + (size_t)brow * 256 + (kt + 2) * 32 + bseg * 16;
            br0 = *(const uint4*)(p);
            br1 = *(const uint4*)(p + 8);
        }
        half8 af[2], bf[4];
        #pragma unroll
        for (int mb = 0; mb < 2; mb++) {
            int row = wr * 32 + mb * 16 + r;
            af[mb] = *(const half8*)(&AQW[(row << 8) + ((kt * 32 + g * 8) ^ ((row & 7) << 3))]);
        }
        #pragma unroll
        for (int nb = 0; nb < 4; nb++) {
            int row = wc * 64 + nb * 16 + r;
            bf[nb] = *(const half8*)(&Bs[kt & 1][row * 32 + ((g ^ ((row >> 1) & 3)) << 3)]);
        }
        // swapped operands: D (g*4+reg) <- bf rows (n=ch), (lane&15) <- af rows (m=px)
        #pragma unroll
        for (int mb = 0; mb < 2; mb++)
            #pragma unroll
            for (int nb = 0; nb < 4; nb++)
                acc[mb][nb] = __builtin_amdgcn_mfma_f32_16x16x32_f16(bf[nb], af[mb], acc[mb][nb], 0, 0, 0);
        __syncthreads();
    }

    // ---- epilogue: qh = acc + cvec -> AQW (A is dead; kt=7 barrier covers reads) ----
    #pragma unroll
    for (int mb = 0; mb < 2; mb++) {
        int row = wr * 32 + mb * 16 + r;
        #pragma unroll
        for (int nb = 0; nb < 4; nb++) {
            int ncol = wc * 64 + nb * 16 + g * 4;
            f32x4 cv = *(const f32x4*)(cvec + ncol);
            half4 h;
            #pragma unroll
            for (int i = 0; i < 4; i++) h[i] = (_Float16)(acc[mb][nb][i] + cv[i]);
            *(half4*)(&AQW[(row << 8) + (ncol ^ ((row & 7) << 3))]) = h;
        }
    }
    __syncthreads();

    // ---- hoisted phase-3 prologue: issue Wv loads + Bs[0] stage (Bs unused in phase 2) ----
    {
        const _Float16* p = wv16 + (size_t)brow * 256 + bseg * 16;
        br0 = *(const uint4*)(p);
        br1 = *(const uint4*)(p + 8);
        *(uint4*)(&Bs[0][brow * 32 + bslot0 * 8]) = br0;
        *(uint4*)(&Bs[0][brow * 32 + bslot1 * 8]) = br1;
        p += 32;
        br0 = *(const uint4*)(p);
        br1 = *(const uint4*)(p + 8);
    }

    // ================= phase 2: gather-attn, w overwrites qh in place =================
    {
        // issue ALL gather loads first (it=1 latency hides under it=0 compute)
        half8 xva[NPTS], xvb[NPTS], xvc[NPTS], xvd[NPTS];
        #pragma unroll
        for (int n = 0; n < NPTS; n++) {
            const _Float16* xr = xt + ((size_t)b * HW + jj0[n]) * 256;
            xva[n] = *(const half8*)(xr + seg * 8);
            xvb[n] = *(const half8*)(xr + 128 + seg * 8);
        }
        #pragma unroll
        for (int n = 0; n < NPTS; n++) {
            const _Float16* xr = xt + ((size_t)b * HW + jj1[n]) * 256;
            xvc[n] = *(const half8*)(xr + seg * 8);
            xvd[n] = *(const half8*)(xr + 128 + seg * 8);
        }

        // ---- it = 0 (pl = pslot) ----
        {
            int pl = pslot;
            int qa0 = (pl << 8) + ((seg * 8)       ^ ((pl & 7) << 3));
            int qa1 = (pl << 8) + ((128 + seg * 8) ^ ((pl & 7) << 3));
            half8 q0 = *(const half8*)(&AQW[qa0]);
            half8 q1 = *(const half8*)(&AQW[qa1]);
            float o0[8], o1[8];
            #pragma unroll
            for (int e = 0; e < 8; e++) { o0[e] = 0.f; o1[e] = 0.f; }
            float asl = 0.f;
            #pragma unroll
            for (int n = 0; n < NPTS; n++) {
                float d = 0.f;
                #pragma unroll
                for (int e = 0; e < 8; e++) d += (float)q0[e] * (float)xva[n][e];
                #pragma unroll
                for (int e = 0; e < 8; e++) d += (float)q1[e] * (float)xvb[n][e];
                d += __shfl_xor(d, 1);
                d += __shfl_xor(d, 2);
                d += __shfl_xor(d, 4);
                d += __shfl_xor(d, 8);
                float a = d + sv0;
                asl += a;
                #pragma unroll
                for (int e = 0; e < 8; e++) o0[e] += a * (float)xva[n][e];
                #pragma unroll
                for (int e = 0; e < 8; e++) o1[e] += a * (float)xvb[n][e];
            }
            half8 h0, h1;
            #pragma unroll
            for (int e = 0; e < 8; e++) { h0[e] = (_Float16)o0[e]; h1[e] = (_Float16)o1[e]; }
            *(half8*)(&AQW[qa0]) = h0;           // same lane's own segment: no cross-lane hazard
            *(half8*)(&AQW[qa1]) = h1;
            if (seg == 0) asf[pl] = asl;
        }

        // ---- it = 1 (pl = 32 + pslot) ----
        {
            int pl = 32 + pslot;
            int qa0 = (pl << 8) + ((seg * 8)       ^ ((pl & 7) << 3));
            int qa1 = (pl << 8) + ((128 + seg * 8) ^ ((pl & 7) << 3));
            half8 q0 = *(const half8*)(&AQW[qa0]);
            half8 q1 = *(const half8*)(&AQW[qa1]);
            float o0[8], o1[8];
            #pragma unroll
            for (int e = 0; e < 8; e++) { o0[e] = 0.f; o1[e] = 0.f; }
            float asl = 0.f;
            #pragma unroll
            for (int n = 0; n < NPTS; n++) {
                float d = 0.f;
                #pragma unroll
                for (int e = 0; e < 8; e++) d += (float)q0[e] * (float)xvc[n][e];
                #pragma unroll
                for (int e = 0; e < 8; e++) d += (float)q1[e] * (float)xvd[n][e];
                d += __shfl_xor(d, 1);
                d += __shfl_xor(d, 2);
                d += __shfl_xor(d, 4);
                d += __shfl_xor(d, 8);
                float a = d + sv1;
                asl += a;
                #pragma unroll
                for (int e = 0; e < 8; e++) o0[e] += a * (float)xvc[n][e];
                #pragma unroll
                for (int e = 0; e < 8; e++) o1[e] += a * (float)xvd[n][e];
            }
            half8 h0, h1;
            #pragma unroll
            for (int e = 0; e < 8; e++) { h0[e] = (_Float16)o0[e]; h1[e] = (_Float16)o1[e]; }
            *(half8*)(&AQW[qa0]) = h0;
            *(half8*)(&AQW[qa1]) = h1;
            if (seg == 0) asf[pl] = asl;
        }
    }
    __syncthreads();   // w + asf + Bs[0] all visible

    // ================= phase 3 k-loop: out = Wv.w + asum*bv =================
    f32x4 acc2[2][4] = {};
    #pragma unroll
    for (int kt = 0; kt < 8; kt++) {
        if (kt < 7) {
            _Float16* B = &Bs[(kt + 1) & 1][0];
            *(uint4*)(&B[brow * 32 + bslot0 * 8]) = br0;
            *(uint4*)(&B[brow * 32 + bslot1 * 8]) = br1;
        }
        if (kt < 6) {
            const _Float16* p = wv16 + (size_t)brow * 256 + (kt + 2) * 32 + bseg * 16;
            br0 = *(const uint4*)(p);
            br1 = *(const uint4*)(p + 8);
        }
        half8 af[2], bf[4];
        #pragma unroll
        for (int mb = 0; mb < 2; mb++) {
            int row = wr * 32 + mb * 16 + r;
            af[mb] = *(const half8*)(&AQW[(row << 8) + ((kt * 32 + g * 8) ^ ((row & 7) << 3))]);
        }
        #pragma unroll
        for (int nb = 0; nb < 4; nb++) {
            int row = wc * 64 + nb * 16 + r;
            bf[nb] = *(const half8*)(&Bs[kt & 1][row * 32 + ((g ^ ((row >> 1) & 3)) << 3)]);
        }
        #pragma unroll
        for (int mb = 0; mb < 2; mb++)
            #pragma unroll
            for (int nb = 0; nb < 4; nb++)
                acc2[mb][nb] = __builtin_amdgcn_mfma_f32_16x16x32_f16(bf[nb], af[mb], acc2[mb][nb], 0, 0, 0);
        __syncthreads();
    }

    // ---- epilogue: out[c][p] = acc2 + asum*bv ----
    #pragma unroll
    for (int mb = 0; mb < 2; mb++) {
        int mrow = wr * 32 + mb * 16 + r;
        float am = asf[mrow];
        float* obase = out + (size_t)b * CH * HW + p0 + mrow;
        #pragma unroll
        for (int nb = 0; nb < 4; nb++) {
            int cb = wc * 64 + nb * 16 + g * 4;
            f32x4 bb = *(const f32x4*)(bv + cb);
            #pragma unroll
            for (int i = 0; i < 4; i++)
                obase[(size_t)(cb + i) * HW] = acc2[mb][nb][i] + am * bb[i];
        }
    }
}

extern "C" void kernel_launch(void* const* d_in, const int* in_sizes, int n_in,
                              void* d_out, int out_size, void* d_ws, size_t ws_size,
                              hipStream_t stream) {
    const float* x  = (const float*)d_in[0];
    const float* Wq = (const float*)d_in[1];
    const float* bq = (const float*)d_in[2];
    const float* Wk = (const float*)d_in[3];
    const float* bk = (const float*)d_in[4];
    const float* Wv = (const float*)d_in[5];
    const float* bv = (const float*)d_in[6];
    const float* Wo = (const float*)d_in[7];
    const float* bo = (const float*)d_in[8];
    (void)in_sizes; (void)n_in; (void)out_size; (void)ws_size;

    char* ws = (char*)d_ws;
    _Float16* xt    = (_Float16*)(ws + WS_XT);
    _Float16* wqk16 = (_Float16*)(ws + WS_WQK);
    _Float16* wv16  = (_Float16*)(ws + WS_WV);
    float*    woq   = (float*)(ws + WS_WOQ);
    float*    bof   = (float*)(ws + WS_BOF);
    float*    cvec  = (float*)(ws + WS_CVEC);
    float*    dvec  = (float*)(ws + WS_DVEC);
    float*    scst  = (float*)(ws + WS_SC);
    float*    svec  = (float*)(ws + WS_SVEC);
    int*      idxb  = (int*)(ws + WS_IDX);

    k_wprep<<<521, 256, 0, stream>>>(Wq, bq, Wk, bk, Wv, bv, Wo, bo,
                                     wqk16, cvec, wv16, woq, bof, dvec, scst);
    k_prep<<<dim3(256, 4), 256, 0, stream>>>(x, woq, bof, dvec, scst, xt, idxb, svec);
    k_fused<<<dim3(256, 4), 512, 0, stream>>>(xt, wqk16, wv16, cvec, bv, idxb, svec,
                                              (float*)d_out);
}

// Round 12
// 88.731 us; speedup vs baseline: 1.1170x; 1.1170x over previous
//
#include <hip/hip_runtime.h>

#define HW   16384
#define CH   256
#define WD   128
#define NPTS 4

typedef _Float16 half8 __attribute__((ext_vector_type(8)));
typedef _Float16 half4 __attribute__((ext_vector_type(4)));
typedef float    f32x4 __attribute__((ext_vector_type(4)));

// ---- workspace layout (bytes) ----
#define WS_XT    0ull            // _Float16 [65536][256]  32 MB  (x transposed, per-pixel)
#define WS_WQK   33554432ull     // _Float16 [256][256]    128 KB (A = Wk^T Wq)
#define WS_WV    33685504ull     // _Float16 [256][256]    128 KB
#define WS_WOQ   33816576ull     // float    [256][8]      8 KB
#define WS_BOF   33824768ull     // float    [8] (64 B pad)
#define WS_CVEC  33824832ull     // float    [256]
#define WS_DVEC  33825856ull     // float    [256]
#define WS_SC    33826880ull     // float    [1] (64 B pad)
#define WS_SVEC  33826944ull     // float    [65536]  256 KB
#define WS_IDX   34089088ull     // int      [4][4][16384]  1 MB

// ---------- weight prep: A=Wk^T Wq fp16, cvec, Wv fp16, woq/bof, dvec, sconst ----------
__global__ void k_wprep(const float* __restrict__ Wq, const float* __restrict__ bq,
                        const float* __restrict__ Wk, const float* __restrict__ bk,
                        const float* __restrict__ Wv, const float* __restrict__ bv,
                        const float* __restrict__ Wo, const float* __restrict__ bo,
                        _Float16* __restrict__ wqk16, float* __restrict__ cvec,
                        _Float16* __restrict__ wv16, float* __restrict__ woq,
                        float* __restrict__ bof, float* __restrict__ dvec,
                        float* __restrict__ scst) {
    int bid = blockIdx.x, t = threadIdx.x;
    if (bid < 256) {                 // A[i][t] = sum_o Wk[o][i]*Wq[o][t]
        int i = bid;
        float s = 0.f;
        for (int o = 0; o < 256; o++) s += Wk[o * 256 + i] * Wq[o * 256 + t];
        wqk16[i * 256 + t] = (_Float16)s;
        if (t == 0) {
            float cs = 0.f;
            for (int o = 0; o < 256; o++) cs += Wk[o * 256 + i] * bq[o];
            cvec[i] = cs;
        }
    } else if (bid < 512) {          // Wv -> fp16
        int r = bid - 256;
        wv16[r * 256 + t] = (_Float16)Wv[r * 256 + t];
    } else if (bid < 520) {          // fused offset weights (fp32, discontinuous path)
        int j = bid - 512;
        float s = 0.f;
        for (int o = 0; o < 256; o++) s += Wo[j * 256 + o] * Wq[o * 256 + t];
        woq[t * 8 + j] = s;
        if (t == 0) {
            float tt = bo[j];
            for (int o = 0; o < 256; o++) tt += Wo[j * 256 + o] * bq[o];
            bof[j] = tt;
        }
    } else {                         // dvec[t] = sum_o bk[o]*Wq[o][t]; sconst = bq.bk
        float s = 0.f;
        for (int o = 0; o < 256; o++) s += bk[o] * Wq[o * 256 + t];
        dvec[t] = s;
        if (t == 0) {
            float sc = 0.f;
            for (int o = 0; o < 256; o++) sc += bq[o] * bk[o];
            scst[0] = sc;
        }
    }
}

// ---------- fused: x -> xt fp16, offsets -> idx (pure f32), s_p ----------
__launch_bounds__(256)
__global__ void k_prep(const float* __restrict__ x, const float* __restrict__ woq,
                       const float* __restrict__ bof, const float* __restrict__ dvec,
                       const float* __restrict__ scst,
                       _Float16* __restrict__ xt, int* __restrict__ idxb,
                       float* __restrict__ svec) {
    __shared__ float    wl[256 * 8];
    __shared__ float    dl[256];
    __shared__ float    bl8[8];
    __shared__ _Float16 tile[64][280];      // pitch 560B: b128 writes spread over all 8 slots
    __shared__ float    red[4][64][8];
    __shared__ float    reds[4][64];

    int t = threadIdx.x;
    for (int i = t; i < 256 * 8; i += 256) wl[i] = woq[i];
    dl[t] = dvec[t];
    if (t < 8) bl8[t] = bof[t];
    __syncthreads();

    int b = blockIdx.y;
    int p0 = blockIdx.x * 64;
    int pl = t & 63, cg = t >> 6;
    const float* xb = x + (size_t)b * CH * HW + p0 + pl;

    float acc[8];
    #pragma unroll
    for (int j = 0; j < 8; j++) acc[j] = 0.f;
    float accs = 0.f;

    for (int i0 = 0; i0 < 64; i0 += 8) {
        half8 hv;
        #pragma unroll
        for (int i = 0; i < 8; i++) {
            int c = cg * 64 + i0 + i;
            float xv = xb[(size_t)c * HW];
            hv[i] = (_Float16)xv;
            accs += dl[c] * xv;
            #pragma unroll
            for (int j = 0; j < 8; j++) acc[j] += wl[c * 8 + j] * xv;
        }
        *(half8*)(&tile[pl][cg * 64 + i0]) = hv;
    }
    #pragma unroll
    for (int j = 0; j < 8; j++) red[cg][pl][j] = acc[j];
    reds[cg][pl] = accs;
    __syncthreads();

    {
        int n = cg, p = p0 + pl;
        float sw_ = bl8[2 * n]     + red[0][pl][2 * n]     + red[1][pl][2 * n]
                                   + red[2][pl][2 * n]     + red[3][pl][2 * n];
        float sh_ = bl8[2 * n + 1] + red[0][pl][2 * n + 1] + red[1][pl][2 * n + 1]
                                   + red[2][pl][2 * n + 1] + red[3][pl][2 * n + 1];
        int h = p >> 7, w = p & 127;
        float rw = fminf(fmaxf((float)w + sw_, 0.f), 127.f);
        float rh = fminf(fmaxf((float)h + sh_, 0.f), 127.f);
        idxb[(b * NPTS + n) * HW + p] = ((int)rh) * WD + (int)rw;
        if (cg == 0)
            svec[b * HW + p] = reds[0][pl] + reds[1][pl] + reds[2][pl] + reds[3][pl] + scst[0];
    }

    {
        int row = t >> 2;
        size_t gbase = ((size_t)(b * HW + p0 + row)) * 256;
        #pragma unroll
        for (int s = 0; s < 8; s++) {
            int seg = (t & 3) + s * 4;
            *(uint4*)(xt + gbase + seg * 8) = *(const uint4*)(&tile[row][seg * 8]);
        }
    }
}

// ---------- fused GEMM1 + gather-attn + GEMM2, v7 = r11 with register cap released ----------
// 512 thr (8 waves), 64 px/block. AQW (32KB): A -> qh -> w in place.
// Bs dbuf (2x16KB). 64.25KB LDS caps residency at 2 blocks/CU regardless of VGPR,
// so no min-waves bound: let the allocator take ~100-128 regs (r10/r11 spilled at 64).
__launch_bounds__(512)
__global__ void k_fused(const _Float16* __restrict__ xt, const _Float16* __restrict__ wqk16,
                        const _Float16* __restrict__ wv16, const float* __restrict__ cvec,
                        const float* __restrict__ bv, const int* __restrict__ idxb,
                        const float* __restrict__ svec, float* __restrict__ out) {
    __shared__ _Float16 AQW[64 * 256];      // 32 KB
    __shared__ _Float16 Bs[2][256 * 32];    // 32 KB
    __shared__ float    asf[64];

    int tid = threadIdx.x;
    int b = blockIdx.y;
    int bx = blockIdx.x;
    int logical = (bx & 7) * 32 + (bx >> 3);    // 256 = 8 XCD * 32, bijective
    int p0 = logical * 64;
    size_t mrow0 = (size_t)b * HW + p0;

    int lane = tid & 63, wid = tid >> 6;
    int wr = wid >> 2, wc = wid & 3;
    int g = lane >> 4, r = lane & 15;

    // ---- stage A (64 px x 256 k) into AQW, swizzled ----
    {
        int row = tid >> 3;
        int c0 = tid & 7;
        const uint4* src = (const uint4*)(xt + (mrow0 + row) * 256);
        #pragma unroll
        for (int s = 0; s < 4; s++) {
            int c8 = c0 + s * 8;
            uint4 v = src[c8];
            *(uint4*)(&AQW[(row << 8) + 8 * (c8 ^ (row & 7))]) = v;
        }
    }

    int brow = tid >> 1, bseg = tid & 1;
    int bslot0 = (bseg * 2)     ^ ((brow >> 1) & 3);
    int bslot1 = (bseg * 2 + 1) ^ ((brow >> 1) & 3);
    uint4 br0, br1;

    // prologue: B(0) -> Bs[0]; B(1) -> regs
    {
        const _Float16* p = wqk16 + (size_t)brow * 256 + bseg * 16;
        br0 = *(const uint4*)(p);
        br1 = *(const uint4*)(p + 8);
        *(uint4*)(&Bs[0][brow * 32 + bslot0 * 8]) = br0;
        *(uint4*)(&Bs[0][brow * 32 + bslot1 * 8]) = br1;
        p += 32;
        br0 = *(const uint4*)(p);
        br1 = *(const uint4*)(p + 8);
    }

    // ---- light prefetch across phase 1 (10 VGPR only: indices + svec) ----
    int seg = tid & 15, pslot = tid >> 4;       // 16 consecutive lanes = one pixel
    int jj0[NPTS], jj1[NPTS];
    #pragma unroll
    for (int n = 0; n < NPTS; n++) {
        jj0[n] = idxb[(b * NPTS + n) * HW + p0 + pslot];
        jj1[n] = idxb[(b * NPTS + n) * HW + p0 + 32 + pslot];
    }
    float sv0 = svec[mrow0 + pslot];
    float sv1 = svec[mrow0 + 32 + pslot];
    __syncthreads();

    // ================= phase 1 k-loop: qh = A.x =================
    f32x4 acc[2][4] = {};
    #pragma unroll
    for (int kt = 0; kt < 8; kt++) {
        if (kt < 7) {
            _Float16* B = &Bs[(kt + 1) & 1][0];
            *(uint4*)(&B[brow * 32 + bslot0 * 8]) = br0;
            *(uint4*)(&B[brow * 32 + bslot1 * 8]) = br1;
        }
        if (kt < 6) {
            const _Float16* p = wqk16 + (size_t)brow * 256 + (kt + 2) * 32 + bseg * 16;
            br0 = *(const uint4*)(p);
            br1 = *(const uint4*)(p + 8);
        }
        half8 af[2], bf[4];
        #pragma unroll
        for (int mb = 0; mb < 2; mb++) {
            int row = wr * 32 + mb * 16 + r;
            af[mb] = *(const half8*)(&AQW[(row << 8) + ((kt * 32 + g * 8) ^ ((row & 7) << 3))]);
        }
        #pragma unroll
        for (int nb = 0; nb < 4; nb++) {
            int row = wc * 64 + nb * 16 + r;
            bf[nb] = *(const half8*)(&Bs[kt & 1][row * 32 + ((g ^ ((row >> 1) & 3)) << 3)]);
        }
        // swapped operands: D (g*4+reg) <- bf rows (n=ch), (lane&15) <- af rows (m=px)
        #pragma unroll
        for (int mb = 0; mb < 2; mb++)
            #pragma unroll
            for (int nb = 0; nb < 4; nb++)
                acc[mb][nb] = __builtin_amdgcn_mfma_f32_16x16x32_f16(bf[nb], af[mb], acc[mb][nb], 0, 0, 0);
        __syncthreads();
    }

    // ---- epilogue: qh = acc + cvec -> AQW (A is dead; kt=7 barrier covers reads) ----
    #pragma unroll
    for (int mb = 0; mb < 2; mb++) {
        int row = wr * 32 + mb * 16 + r;
        #pragma unroll
        for (int nb = 0; nb < 4; nb++) {
            int ncol = wc * 64 + nb * 16 + g * 4;
            f32x4 cv = *(const f32x4*)(cvec + ncol);
            half4 h;
            #pragma unroll
            for (int i = 0; i < 4; i++) h[i] = (_Float16)(acc[mb][nb][i] + cv[i]);
            *(half4*)(&AQW[(row << 8) + (ncol ^ ((row & 7) << 3))]) = h;
        }
    }
    __syncthreads();

    // ---- hoisted phase-3 prologue: issue Wv loads + Bs[0] stage (Bs unused in phase 2) ----
    {
        const _Float16* p = wv16 + (size_t)brow * 256 + bseg * 16;
        br0 = *(const uint4*)(p);
        br1 = *(const uint4*)(p + 8);
        *(uint4*)(&Bs[0][brow * 32 + bslot0 * 8]) = br0;
        *(uint4*)(&Bs[0][brow * 32 + bslot1 * 8]) = br1;
        p += 32;
        br0 = *(const uint4*)(p);
        br1 = *(const uint4*)(p + 8);
    }

    // ================= phase 2: gather-attn, w overwrites qh in place =================
    {
        // issue ALL gather loads first (it=1 latency hides under it=0 compute)
        half8 xva[NPTS], xvb[NPTS], xvc[NPTS], xvd[NPTS];
        #pragma unroll
        for (int n = 0; n < NPTS; n++) {
            const _Float16* xr = xt + ((size_t)b * HW + jj0[n]) * 256;
            xva[n] = *(const half8*)(xr + seg * 8);
            xvb[n] = *(const half8*)(xr + 128 + seg * 8);
        }
        #pragma unroll
        for (int n = 0; n < NPTS; n++) {
            const _Float16* xr = xt + ((size_t)b * HW + jj1[n]) * 256;
            xvc[n] = *(const half8*)(xr + seg * 8);
            xvd[n] = *(const half8*)(xr + 128 + seg * 8);
        }

        // ---- it = 0 (pl = pslot) ----
        {
            int pl = pslot;
            int qa0 = (pl << 8) + ((seg * 8)       ^ ((pl & 7) << 3));
            int qa1 = (pl << 8) + ((128 + seg * 8) ^ ((pl & 7) << 3));
            half8 q0 = *(const half8*)(&AQW[qa0]);
            half8 q1 = *(const half8*)(&AQW[qa1]);
            float o0[8], o1[8];
            #pragma unroll
            for (int e = 0; e < 8; e++) { o0[e] = 0.f; o1[e] = 0.f; }
            float asl = 0.f;
            #pragma unroll
            for (int n = 0; n < NPTS; n++) {
                float d = 0.f;
                #pragma unroll
                for (int e = 0; e < 8; e++) d += (float)q0[e] * (float)xva[n][e];
                #pragma unroll
                for (int e = 0; e < 8; e++) d += (float)q1[e] * (float)xvb[n][e];
                d += __shfl_xor(d, 1);
                d += __shfl_xor(d, 2);
                d += __shfl_xor(d, 4);
                d += __shfl_xor(d, 8);
                float a = d + sv0;
                asl += a;
                #pragma unroll
                for (int e = 0; e < 8; e++) o0[e] += a * (float)xva[n][e];
                #pragma unroll
                for (int e = 0; e < 8; e++) o1[e] += a * (float)xvb[n][e];
            }
            half8 h0, h1;
            #pragma unroll
            for (int e = 0; e < 8; e++) { h0[e] = (_Float16)o0[e]; h1[e] = (_Float16)o1[e]; }
            *(half8*)(&AQW[qa0]) = h0;           // same lane's own segment: no cross-lane hazard
            *(half8*)(&AQW[qa1]) = h1;
            if (seg == 0) asf[pl] = asl;
        }

        // ---- it = 1 (pl = 32 + pslot) ----
        {
            int pl = 32 + pslot;
            int qa0 = (pl << 8) + ((seg * 8)       ^ ((pl & 7) << 3));
            int qa1 = (pl << 8) + ((128 + seg * 8) ^ ((pl & 7) << 3));
            half8 q0 = *(const half8*)(&AQW[qa0]);
            half8 q1 = *(const half8*)(&AQW[qa1]);
            float o0[8], o1[8];
            #pragma unroll
            for (int e = 0; e < 8; e++) { o0[e] = 0.f; o1[e] = 0.f; }
            float asl = 0.f;
            #pragma unroll
            for (int n = 0; n < NPTS; n++) {
                float d = 0.f;
                #pragma unroll
                for (int e = 0; e < 8; e++) d += (float)q0[e] * (float)xvc[n][e];
                #pragma unroll
                for (int e = 0; e < 8; e++) d += (float)q1[e] * (float)xvd[n][e];
                d += __shfl_xor(d, 1);
                d += __shfl_xor(d, 2);
                d += __shfl_xor(d, 4);
                d += __shfl_xor(d, 8);
                float a = d + sv1;
                asl += a;
                #pragma unroll
                for (int e = 0; e < 8; e++) o0[e] += a * (float)xvc[n][e];
                #pragma unroll
                for (int e = 0; e < 8; e++) o1[e] += a * (float)xvd[n][e];
            }
            half8 h0, h1;
            #pragma unroll
            for (int e = 0; e < 8; e++) { h0[e] = (_Float16)o0[e]; h1[e] = (_Float16)o1[e]; }
            *(half8*)(&AQW[qa0]) = h0;
            *(half8*)(&AQW[qa1]) = h1;
            if (seg == 0) asf[pl] = asl;
        }
    }
    __syncthreads();   // w + asf + Bs[0] all visible

    // ================= phase 3 k-loop: out = Wv.w + asum*bv =================
    f32x4 acc2[2][4] = {};
    #pragma unroll
    for (int kt = 0; kt < 8; kt++) {
        if (kt < 7) {
            _Float16* B = &Bs[(kt + 1) & 1][0];
            *(uint4*)(&B[brow * 32 + bslot0 * 8]) = br0;
            *(uint4*)(&B[brow * 32 + bslot1 * 8]) = br1;
        }
        if (kt < 6) {
            const _Float16* p = wv16 + (size_t)brow * 256 + (kt + 2) * 32 + bseg * 16;
            br0 = *(const uint4*)(p);
            br1 = *(const uint4*)(p + 8);
        }
        half8 af[2], bf[4];
        #pragma unroll
        for (int mb = 0; mb < 2; mb++) {
            int row = wr * 32 + mb * 16 + r;
            af[mb] = *(const half8*)(&AQW[(row << 8) + ((kt * 32 + g * 8) ^ ((row & 7) << 3))]);
        }
        #pragma unroll
        for (int nb = 0; nb < 4; nb++) {
            int row = wc * 64 + nb * 16 + r;
            bf[nb] = *(const half8*)(&Bs[kt & 1][row * 32 + ((g ^ ((row >> 1) & 3)) << 3)]);
        }
        #pragma unroll
        for (int mb = 0; mb < 2; mb++)
            #pragma unroll
            for (int nb = 0; nb < 4; nb++)
                acc2[mb][nb] = __builtin_amdgcn_mfma_f32_16x16x32_f16(bf[nb], af[mb], acc2[mb][nb], 0, 0, 0);
        __syncthreads();
    }

    // ---- epilogue: out[c][p] = acc2 + asum*bv ----
    #pragma unroll
    for (int mb = 0; mb < 2; mb++) {
        int mrow = wr * 32 + mb * 16 + r;
        float am = asf[mrow];
        float* obase = out + (size_t)b * CH * HW + p0 + mrow;
        #pragma unroll
        for (int nb = 0; nb < 4; nb++) {
            int cb = wc * 64 + nb * 16 + g * 4;
            f32x4 bb = *(const f32x4*)(bv + cb);
            #pragma unroll
            for (int i = 0; i < 4; i++)
                obase[(size_t)(cb + i) * HW] = acc2[mb][nb][i] + am * bb[i];
        }
    }
}

extern "C" void kernel_launch(void* const* d_in, const int* in_sizes, int n_in,
                              void* d_out, int out_size, void* d_ws, size_t ws_size,
                              hipStream_t stream) {
    const float* x  = (const float*)d_in[0];
    const float* Wq = (const float*)d_in[1];
    const float* bq = (const float*)d_in[2];
    const float* Wk = (const float*)d_in[3];
    const float* bk = (const float*)d_in[4];
    const float* Wv = (const float*)d_in[5];
    const float* bv = (const float*)d_in[6];
    const float* Wo = (const float*)d_in[7];
    const float* bo = (const float*)d_in[8];
    (void)in_sizes; (void)n_in; (void)out_size; (void)ws_size;

    char* ws = (char*)d_ws;
    _Float16* xt    = (_Float16*)(ws + WS_XT);
    _Float16* wqk16 = (_Float16*)(ws + WS_WQK);
    _Float16* wv16  = (_Float16*)(ws + WS_WV);
    float*    woq   = (float*)(ws + WS_WOQ);
    float*    bof   = (float*)(ws + WS_BOF);
    float*    cvec  = (float*)(ws + WS_CVEC);
    float*    dvec  = (float*)(ws + WS_DVEC);
    float*    scst  = (float*)(ws + WS_SC);
    float*    svec  = (float*)(ws + WS_SVEC);
    int*      idxb  = (int*)(ws + WS_IDX);

    k_wprep<<<521, 256, 0, stream>>>(Wq, bq, Wk, bk, Wv, bv, Wo, bo,
                                     wqk16, cvec, wv16, woq, bof, dvec, scst);
    k_prep<<<dim3(256, 4), 256, 0, stream>>>(x, woq, bof, dvec, scst, xt, idxb, svec);
    k_fused<<<dim3(256, 4), 512, 0, stream>>>(xt, wqk16, wv16, cvec, bv, idxb, svec,
                                              (float*)d_out);
}